// Round 11
// baseline (247.300 us; speedup 1.0000x reference)
//
#include <hip/hip_runtime.h>
#include <math.h>

#define BSZ    256
#define GRID_N 49
#define LSTMH  512
#define CNN_C  2048
#define PROJ   512
#define KAUG   2560               // [cnn k=0..2047 | lstm k=2048..2559]
#define M_TOT  12544              // 256*49
#define BK2    32
#define KT2    (KAUG / BK2)       // 80 k-tiles (0..63 cnn, 64..79 lstm)

// ---- fast-path geometry: 128x128 tile, BK=32 ----
#define MT2    128
#define NT2    128
#define NBLK2  ((M_TOT / MT2) * (PROJ / NT2)) // 392 = 8*49; 48 KB LDS -> 3 blk/CU, all fit

// ---- fallback geometry ----
#define MT     64
#define NT     128
#define BK     64
#define KTILES (KAUG / BK)
#define NBLK   ((M_TOT / MT) * (PROJ / NT))   // 784

#define WBLK   640                            // 512*320 W chunks / 256

typedef short bf16x8 __attribute__((ext_vector_type(8)));
typedef float f32x4  __attribute__((ext_vector_type(4)));

static __device__ __forceinline__ unsigned short bf16_rne(float f) {
    unsigned int u = __float_as_uint(f);
    u = u + 0x7FFFu + ((u >> 16) & 1u);
    return (unsigned short)(u >> 16);
}
static __device__ __forceinline__ uint4 pack8f(const float* f) {
    uint4 o;
    o.x = (unsigned int)bf16_rne(f[0]) | ((unsigned int)bf16_rne(f[1]) << 16);
    o.y = (unsigned int)bf16_rne(f[2]) | ((unsigned int)bf16_rne(f[3]) << 16);
    o.z = (unsigned int)bf16_rne(f[4]) | ((unsigned int)bf16_rne(f[5]) << 16);
    o.w = (unsigned int)bf16_rne(f[6]) | ((unsigned int)bf16_rne(f[7]) << 16);
    return o;
}
static __device__ __forceinline__ float tanh_fast(float x) {
    float e = __expf(2.f * x);
    return 1.f - 2.f / (e + 1.f);
}
// async 16B global->LDS (wave-uniform LDS base + lane*16)
static __device__ __forceinline__ void glds16(const void* g, void* l) {
    __builtin_amdgcn_global_load_lds(
        (const __attribute__((address_space(1))) unsigned int*)g,
        (__attribute__((address_space(3))) unsigned int*)l, 16, 0, 0);
}

// ==== prep: W_aug (512 x 2560) fp32 -> bf16(RNE); blocks 0..48 also zero out ====
// wsA/wsL eliminated this round: cnn/lstm are staged fp32 by gemm10 via glds and
// converted on the LDS->register read. prep traffic: 208 MB -> 11 MB (~4 us).
__global__ __launch_bounds__(256) void prep_w(const float* __restrict__ Wc,
                                              const float* __restrict__ Wl,
                                              unsigned short* __restrict__ wsW,
                                              float* __restrict__ out) {
    const int bid = blockIdx.x, t = threadIdx.x;
    if (bid < 49) out[bid * 256 + t] = 0.f;     // 49*256 = 12544 exactly
    int c  = bid * 256 + t;
    int p  = c / 320;
    int kc = (c % 320) * 8;
    const float* src = (kc < CNN_C) ? (Wc + (size_t)p * CNN_C + kc)
                                    : (Wl + (size_t)p * LSTMH + (kc - CNN_C));
    float f[8];
    *(float4*)&f[0] = ((const float4*)src)[0];
    *(float4*)&f[4] = ((const float4*)src)[1];
    *(uint4*)(wsW + (size_t)p * KAUG + kc) = pack8f(f);
}

// ==== fast-path GEMM: counted-vmcnt 2-ahead (gemm8 schedule) + fp32-A glds ====
// A staged as fp32 directly from cnn/lstm (no conversion pass): glds is async,
// zero VALU; fragments converted LDS->reg with v_cvt_pk_bf16_f32 (RNE, verified
// numerically in round 9's refcheck-passing path). BK=32 so fp32-A dbuf fits:
// LDS = 32(A) + 16(B) = 48 KB -> 3 blocks/CU AND the queue-never-empties
// pipeline — the two proven mechanisms finally combined. Per iter: wait
// vmcnt(6) (tile kt landed, kt+1's 6 loads in flight) -> bar -> 16 MFMA ->
// bar -> stage(kt+2). cnn re-reads (x4 n-blocks) are same-XCD L2 hits (1 MB
// panel << 4 MB L2, existing swizzle).
__global__ __launch_bounds__(256, 3) void gemm10(
    const float* __restrict__ lstm, const float* __restrict__ cnn,
    const unsigned short* __restrict__ wsW,
    const float* __restrict__ bl, const float* __restrict__ bc,
    const float* __restrict__ wat, float* __restrict__ out)
{
    __shared__ float          Ab[2][MT2][BK2];   // 32 KB (fp32)
    __shared__ unsigned short Bb[2][NT2][BK2];   // 16 KB (bf16)

    const int t   = threadIdx.x;
    const int w   = t >> 6;
    const int l   = t & 63;
    const int q   = l >> 4;          // k-group 0..3 (8 k each = full BK2)
    const int r16 = l & 15;
    const int wr  = w >> 1;          // wave grid 2x2, wave owns 64x64
    const int wc  = w & 1;

    // XCD-bijective swizzle: 392 = 8*49; 4 n-blocks of one m-panel stay adjacent.
    const int bid = (int)blockIdx.x;
    const int swz = (bid & 7) * (NBLK2 / 8) + (bid >> 3);
    const int m0  = (swz >> 2) * MT2;
    const int n0  = (swz & 3) * NT2;

    // A glds lane geometry: instr = 8 rows x 8 chunks(16B=4f); swizzle
    // LDS[row][c] = G[row][c ^ (row&7)], source-folded (rowbase%8==0):
    const int aro = l >> 3;                   // row offset 0..7
    const int cga = (l & 7) ^ aro;            // source chunk
    // B glds lane geometry: instr = 16 rows x 4 chunks(16B=8bf16); swizzle
    // LDS[row][c] = G[row][c ^ ((row>>2)&3)], source-folded (rowbase%16==0):
    const int bro = l >> 2;                   // row offset 0..15
    const int cgb = (l & 3) ^ ((l >> 4) & 3); // source chunk

    // Per-lane global bases (row constant across tiles; only k advances).
    // cnn is [B][49][C] contiguous => flat row index IS m-row (no div).
    const float* srcA[4]; const float* srcL[4]; const unsigned short* srcB[2];
    #pragma unroll
    for (int j = 0; j < 4; ++j) {
        const int grow = m0 + w * 32 + j * 8 + aro;
        srcA[j] = cnn  + (size_t)grow * CNN_C + cga * 4;
        srcL[j] = lstm + (size_t)(grow / 49) * LSTMH + cga * 4;
    }
    #pragma unroll
    for (int j = 0; j < 2; ++j) {
        const int rowb = n0 + w * 32 + j * 16 + bro;
        srcB[j] = wsW + (size_t)rowb * KAUG + cgb * 8;
    }

    // stage = exactly 6 glds/wave (2 B + 4 A) -- uniform for vmcnt math
    auto stage = [&](int kt, int bufi) {
        const int k0 = kt * BK2;
        #pragma unroll
        for (int j = 0; j < 2; ++j)
            glds16(srcB[j] + k0, &Bb[bufi][w * 32 + j * 16][0]);
        if (kt < 64) {
            #pragma unroll
            for (int j = 0; j < 4; ++j)
                glds16(srcA[j] + k0, &Ab[bufi][w * 32 + j * 8][0]);
        } else {
            const int k0l = k0 - CNN_C;
            #pragma unroll
            for (int j = 0; j < 4; ++j)
                glds16(srcL[j] + k0l, &Ab[bufi][w * 32 + j * 8][0]);
        }
    };

    // Fragment address constants
    int Ra[4], ca0[4], ca1[4], Rb_[4], cb[4];
    #pragma unroll
    for (int mt = 0; mt < 4; ++mt) {
        Ra[mt]  = wr * 64 + mt * 16 + r16;
        ca0[mt] = (2 * q)     ^ (Ra[mt] & 7);
        ca1[mt] = (2 * q + 1) ^ (Ra[mt] & 7);
    }
    #pragma unroll
    for (int nt = 0; nt < 4; ++nt) {
        Rb_[nt] = wc * 64 + nt * 16 + r16;
        cb[nt]  = q ^ ((Rb_[nt] >> 2) & 3);
    }

    f32x4 acc[4][4];
    #pragma unroll
    for (int mt = 0; mt < 4; ++mt)
        #pragma unroll
        for (int nt = 0; nt < 4; ++nt)
            acc[mt][nt] = (f32x4){0.f, 0.f, 0.f, 0.f};

    // prologue: tiles 0 and 1 in flight (12 glds outstanding)
    stage(0, 0);
    stage(1, 1);

    for (int kt = 0; kt < KT2; ++kt) {
        const int cur = kt & 1;
        if (kt + 1 < KT2) {
            asm volatile("s_waitcnt vmcnt(6)" ::: "memory");  // tile kt landed
        } else {
            asm volatile("s_waitcnt vmcnt(0)" ::: "memory");
        }
        __builtin_amdgcn_s_barrier();
        bf16x8 af[4], bfr[4];
        #pragma unroll
        for (int mt = 0; mt < 4; ++mt) {      // A: fp32 LDS -> bf16 regs (RNE)
            const float* ar = &Ab[cur][Ra[mt]][0];
            const float4 xa = *(const float4*)(ar + ca0[mt] * 4);
            const float4 xb = *(const float4*)(ar + ca1[mt] * 4);
            uint4 o;
            asm("v_cvt_pk_bf16_f32 %0, %1, %2" : "=v"(o.x) : "v"(xa.x), "v"(xa.y));
            asm("v_cvt_pk_bf16_f32 %0, %1, %2" : "=v"(o.y) : "v"(xa.z), "v"(xa.w));
            asm("v_cvt_pk_bf16_f32 %0, %1, %2" : "=v"(o.z) : "v"(xb.x), "v"(xb.y));
            asm("v_cvt_pk_bf16_f32 %0, %1, %2" : "=v"(o.w) : "v"(xb.z), "v"(xb.w));
            af[mt] = *(bf16x8*)&o;
        }
        #pragma unroll
        for (int nt = 0; nt < 4; ++nt)
            bfr[nt] = *(const bf16x8*)&Bb[cur][Rb_[nt]][cb[nt] * 8];
        #pragma unroll
        for (int mt = 0; mt < 4; ++mt)
            #pragma unroll
            for (int nt = 0; nt < 4; ++nt)
                acc[mt][nt] = __builtin_amdgcn_mfma_f32_16x16x32_bf16(
                    af[mt], bfr[nt], acc[mt][nt], 0, 0, 0);
        __builtin_amdgcn_s_barrier();         // all waves' reads of buf[cur] done
        if (kt + 2 < KT2) stage(kt + 2, cur); // refill buffer just consumed
    }

    // ---- epilogue: tanh + w_attn partial dot over this block's 128 cols ----
    float* zpf = (float*)&Ab[0][0][0];        // reuse LDS (tiles dead)
    float part[4][4];
    #pragma unroll
    for (int mt = 0; mt < 4; ++mt)
        #pragma unroll
        for (int rr = 0; rr < 4; ++rr) part[mt][rr] = 0.f;
    #pragma unroll
    for (int nt = 0; nt < 4; ++nt) {
        const int p = n0 + wc * 64 + nt * 16 + r16;
        const float bb = bl[p] + bc[p];
        const float wa = wat[p];
        #pragma unroll
        for (int mt = 0; mt < 4; ++mt)
            #pragma unroll
            for (int rr = 0; rr < 4; ++rr)
                part[mt][rr] += tanh_fast(acc[mt][nt][rr] + bb) * wa;
    }
    #pragma unroll
    for (int mt = 0; mt < 4; ++mt)
        #pragma unroll
        for (int rr = 0; rr < 4; ++rr) {
            float v = part[mt][rr];
            v += __shfl_xor(v, 1);
            v += __shfl_xor(v, 2);
            v += __shfl_xor(v, 4);
            v += __shfl_xor(v, 8);            // sum over 16 cols (r16 group)
            if (r16 == 0) zpf[wc * MT2 + wr * 64 + mt * 16 + q * 4 + rr] = v;
        }
    __syncthreads();
    if (t < MT2) {
        const float v = zpf[t] + zpf[MT2 + t];
        const int row = m0 + t;
        const int b2  = row / 49;
        const int g2  = row - b2 * 49;
        atomicAdd(&out[g2 * BSZ + b2], v);    // scrambled position
    }
}

// ==== fallback (no workspace): verified convert-in-kernel GEMM ====
__global__ __launch_bounds__(256, 4) void gemm_k(
    const float* __restrict__ lstm, const float* __restrict__ cnn,
    const float* __restrict__ Wc,   const float* __restrict__ Wl,
    const float* __restrict__ bl,   const float* __restrict__ bc,
    const float* __restrict__ wat,  float* __restrict__ out)
{
    __shared__ unsigned short Ash[MT][BK];
    __shared__ unsigned short Bsh[NT][BK];
    __shared__ float zp[4][MT];

    const int t   = threadIdx.x;
    const int w   = t >> 6;
    const int l   = t & 63;
    const int q   = l >> 4;
    const int r16 = l & 15;

    const int bid = (int)blockIdx.x;
    const int swz = (bid & 7) * (NBLK / 8) + (bid >> 3);
    const int m0 = (swz >> 2) * MT;
    const int n0 = (swz & 3) * NT;

    const int ra  = t >> 2;
    const int ca0 = t & 3;
    const int sa  = ra & 7;
    const int grow = m0 + ra;
    const int ab   = grow / 49;
    const int ag   = grow - ab * 49;
    const float* cnnb  = cnn + ((size_t)ab * GRID_N + ag) * CNN_C;
    const float* lstmb = lstm + (size_t)ab * LSTMH;

    f32x4 acc[4][2];
    #pragma unroll
    for (int mt = 0; mt < 4; ++mt)
        #pragma unroll
        for (int nt = 0; nt < 2; ++nt)
            acc[mt][nt] = (f32x4){0.f, 0.f, 0.f, 0.f};

    float4 fa0, fa1, fa2, fa3;

    auto a_load = [&](int k0) {
        const float* s = (k0 < CNN_C) ? (cnnb + k0) : (lstmb + (k0 - CNN_C));
        const float4* p0 = (const float4*)(s + ca0 * 8);
        const float4* p1 = (const float4*)(s + (ca0 + 4) * 8);
        fa0 = p0[0]; fa1 = p0[1];
        fa2 = p1[0]; fa3 = p1[1];
    };
    auto a_write = [&]() {
        float f[8];
        *(float4*)&f[0] = fa0; *(float4*)&f[4] = fa1;
        *(uint4*)&Ash[ra][(ca0 ^ sa) * 8] = pack8f(f);
        *(float4*)&f[0] = fa2; *(float4*)&f[4] = fa3;
        *(uint4*)&Ash[ra][((ca0 + 4) ^ sa) * 8] = pack8f(f);
    };
    auto b_stage = [&](int k0) {
        const int rb = t >> 1;
        const int hb = t & 1;
        const float* s = (k0 < CNN_C) ? (Wc + (size_t)(n0 + rb) * CNN_C + k0)
                                      : (Wl + (size_t)(n0 + rb) * LSTMH + (k0 - CNN_C));
        const int sw = rb & 7;
        #pragma unroll
        for (int c = 0; c < 4; ++c) {
            const int cc = hb * 4 + c;
            float f[8];
            *(float4*)&f[0] = ((const float4*)(s + cc * 8))[0];
            *(float4*)&f[4] = ((const float4*)(s + cc * 8))[1];
            *(uint4*)&Bsh[rb][(cc ^ sw) * 8] = pack8f(f);
        }
    };

    a_load(0);
    a_write();
    b_stage(0);

    for (int kt = 0; kt < KTILES; ++kt) {
        __syncthreads();
        const bool more = (kt + 1 < KTILES);
        if (more) a_load((kt + 1) * BK);
        #pragma unroll
        for (int ks = 0; ks < 2; ++ks) {
            const int cp = ((ks * 4 + q) ^ (r16 & 7)) * 8;
            bf16x8 af[4], bfr[2];
            #pragma unroll
            for (int mt = 0; mt < 4; ++mt)
                af[mt] = *(const bf16x8*)&Ash[mt * 16 + r16][cp];
            #pragma unroll
            for (int nt = 0; nt < 2; ++nt)
                bfr[nt] = *(const bf16x8*)&Bsh[w * 32 + nt * 16 + r16][cp];
            #pragma unroll
            for (int mt = 0; mt < 4; ++mt)
                #pragma unroll
                for (int nt = 0; nt < 2; ++nt)
                    acc[mt][nt] = __builtin_amdgcn_mfma_f32_16x16x32_bf16(
                        af[mt], bfr[nt], acc[mt][nt], 0, 0, 0);
        }
        __syncthreads();
        if (more) { a_write(); b_stage((kt + 1) * BK); }
    }

    float part[4][4];
    #pragma unroll
    for (int mt = 0; mt < 4; ++mt)
        #pragma unroll
        for (int rr = 0; rr < 4; ++rr) part[mt][rr] = 0.f;
    #pragma unroll
    for (int nt = 0; nt < 2; ++nt) {
        const int p = n0 + w * 32 + nt * 16 + r16;
        const float bb = bl[p] + bc[p];
        const float wa = wat[p];
        #pragma unroll
        for (int mt = 0; mt < 4; ++mt)
            #pragma unroll
            for (int rr = 0; rr < 4; ++rr)
                part[mt][rr] += tanh_fast(acc[mt][nt][rr] + bb) * wa;
    }
    #pragma unroll
    for (int mt = 0; mt < 4; ++mt)
        #pragma unroll
        for (int rr = 0; rr < 4; ++rr) {
            float v = part[mt][rr];
            v += __shfl_xor(v, 1);
            v += __shfl_xor(v, 2);
            v += __shfl_xor(v, 4);
            v += __shfl_xor(v, 8);
            if (r16 == 0) zp[w][mt * 16 + q * 4 + rr] = v;
        }
    __syncthreads();
    if (t < MT) {
        const float v = zp[0][t] + zp[1][t] + zp[2][t] + zp[3][t];
        const int row = m0 + t;
        const int b2  = row / 49;
        const int g2  = row - b2 * 49;
        atomicAdd(&out[g2 * BSZ + b2], v);
    }
}

// Row softmax over 49 elements, in place. One wave per row.
__global__ __launch_bounds__(64) void softmax_rows(float* __restrict__ out)
{
    const int i = blockIdx.x;
    const int j = threadIdx.x;
    float x = (j < GRID_N) ? out[i * GRID_N + j] : -1e30f;
    float m = x;
    #pragma unroll
    for (int off = 32; off > 0; off >>= 1) m = fmaxf(m, __shfl_xor(m, off));
    float e = (j < GRID_N) ? __expf(x - m) : 0.f;
    float s = e;
    #pragma unroll
    for (int off = 32; off > 0; off >>= 1) s += __shfl_xor(s, off);
    if (j < GRID_N) out[i * GRID_N + j] = e / s;
}

extern "C" void kernel_launch(void* const* d_in, const int* in_sizes, int n_in,
                              void* d_out, int out_size, void* d_ws, size_t ws_size,
                              hipStream_t stream)
{
    const float* lstm = (const float*)d_in[0];
    const float* cnn  = (const float*)d_in[1];
    const float* Wl   = (const float*)d_in[2];
    const float* bl   = (const float*)d_in[3];
    const float* Wc   = (const float*)d_in[4];
    const float* bc   = (const float*)d_in[5];
    const float* wat  = (const float*)d_in[6];
    float* out = (float*)d_out;

    const size_t szW = (size_t)PROJ * KAUG * sizeof(unsigned short);    // 2.62 MB

    if (ws_size >= szW) {
        unsigned short* wsW = (unsigned short*)d_ws;
        prep_w<<<dim3(WBLK), dim3(256), 0, stream>>>(Wc, Wl, wsW, out);
        gemm10<<<dim3(NBLK2), dim3(256), 0, stream>>>(lstm, cnn, wsW, bl, bc, wat, out);
    } else {
        hipMemsetAsync(out, 0, (size_t)out_size * sizeof(float), stream);
        gemm_k<<<dim3(NBLK), dim3(256), 0, stream>>>(lstm, cnn, Wc, Wl, bl, bc, wat, out);
    }
    softmax_rows<<<dim3(BSZ), dim3(64), 0, stream>>>(out);
}

// Round 12
// 218.026 us; speedup vs baseline: 1.1343x; 1.1343x over previous
//
#include <hip/hip_runtime.h>
#include <math.h>

#define BSZ    256
#define GRID_N 49
#define LSTMH  512
#define CNN_C  2048
#define PROJ   512
#define KAUG   2560               // [cnn k=0..2047 | lstm k=2048..2559]
#define M_TOT  12544              // 256*49
#define BK     64

// ---- fast-path geometry: 128x128 tile, K = CNN_C only (lstm split out) ----
#define MT2    128
#define NT2    128
#define KT11   (CNN_C / BK)       // 32 k-tiles
#define NBLK2  ((M_TOT / MT2) * (PROJ / NT2)) // 392 = 8*49

// ---- h_gemm geometry: H = lstm @ Wl^T, 256x512x512 ----
#define KTH    (LSTMH / BK)       // 8 k-tiles

// ---- fallback geometry ----
#define MT     64
#define NT     128
#define KTILES (KAUG / BK)
#define NBLK   ((M_TOT / MT) * (PROJ / NT))   // 784

// ---- prep grid (round-10 verified one-shot layout — DO NOT TOUCH) ----
#define ACHUNKS (M_TOT * CNN_C / 8)           // 3,211,264 cnn 8-float chunks
#define LCHUNKS (BSZ * LSTMH / 8)             // 16,384 lstm chunks
#define ABLK    ((ACHUNKS + LCHUNKS) / 256)   // 12,608
#define WBLK    640                           // 512*320 W chunks / 256
#define PBLK    (ABLK + WBLK)                 // 13,248

typedef short bf16x8 __attribute__((ext_vector_type(8)));
typedef float f32x4  __attribute__((ext_vector_type(4)));

static __device__ __forceinline__ unsigned short bf16_rne(float f) {
    unsigned int u = __float_as_uint(f);
    u = u + 0x7FFFu + ((u >> 16) & 1u);
    return (unsigned short)(u >> 16);
}
static __device__ __forceinline__ uint4 pack8f(const float* f) {
    uint4 o;
    o.x = (unsigned int)bf16_rne(f[0]) | ((unsigned int)bf16_rne(f[1]) << 16);
    o.y = (unsigned int)bf16_rne(f[2]) | ((unsigned int)bf16_rne(f[3]) << 16);
    o.z = (unsigned int)bf16_rne(f[4]) | ((unsigned int)bf16_rne(f[5]) << 16);
    o.w = (unsigned int)bf16_rne(f[6]) | ((unsigned int)bf16_rne(f[7]) << 16);
    return o;
}
static __device__ __forceinline__ float tanh_fast(float x) {
    float e = __expf(2.f * x);
    return 1.f - 2.f / (e + 1.f);
}
// async 16B global->LDS (wave-uniform LDS base + lane*16)
static __device__ __forceinline__ void glds16(const void* g, void* l) {
    __builtin_amdgcn_global_load_lds(
        (const __attribute__((address_space(1))) unsigned int*)g,
        (__attribute__((address_space(3))) unsigned int*)l, 16, 0, 0);
}

// ==== prep: zero out + convert W_aug, cnn, lstm to bf16 (ONE-SHOT, round-10) ====
// ~49 us measured-by-subtraction. Grid-stride "improvements" regressed twice
// (48.6 -> 59.6); leave as is.
__global__ __launch_bounds__(256) void prep_all(
    const float* __restrict__ cnn, const float* __restrict__ lstm,
    const float* __restrict__ Wc,  const float* __restrict__ Wl,
    unsigned short* __restrict__ wsW, unsigned short* __restrict__ wsA,
    unsigned short* __restrict__ wsL, float* __restrict__ out)
{
    const int bid = blockIdx.x, t = threadIdx.x;
    if (bid < 49) out[bid * 256 + t] = 0.f;     // 49*256 = 12544 exactly
    float f[8];
    if (bid < ABLK) {                           // cnn / lstm: pure linear convert
        const int c = bid * 256 + t;
        const float* src; unsigned short* dst;
        if (c < ACHUNKS) { src = cnn  + (size_t)c * 8; dst = wsA + (size_t)c * 8; }
        else { const int c2 = c - ACHUNKS; src = lstm + (size_t)c2 * 8; dst = wsL + (size_t)c2 * 8; }
        *(float4*)&f[0] = ((const float4*)src)[0];
        *(float4*)&f[4] = ((const float4*)src)[1];
        *(uint4*)dst = pack8f(f);
    } else {                                    // W_aug layout [512][2560]
        const int c  = (bid - ABLK) * 256 + t;
        const int p  = c / 320;
        const int kc = (c % 320) * 8;
        const float* src = (kc < CNN_C) ? (Wc + (size_t)p * CNN_C + kc)
                                        : (Wl + (size_t)p * LSTMH + (kc - CNN_C));
        *(float4*)&f[0] = ((const float4*)src)[0];
        *(float4*)&f[4] = ((const float4*)src)[1];
        *(uint4*)(wsW + (size_t)p * KAUG + kc) = pack8f(f);
    }
}

// ==== h_gemm: H[256][512] = lstm @ Wl^T (fp32 out). Removes the 49x-replicated
// lstm K-segment from the main GEMM (20% of its MFMA + B-traffic). Same
// counted-vmcnt 2-ahead structure as gemm8; 8 blocks (2x4), 8 k-tiles. ====
__global__ __launch_bounds__(256, 2) void h_gemm(
    const unsigned short* __restrict__ wsL, const unsigned short* __restrict__ wsW,
    float* __restrict__ wsH)
{
    __shared__ unsigned short Ab[2][MT2][BK];   // 32 KB
    __shared__ unsigned short Bb[2][NT2][BK];   // 32 KB

    const int t   = threadIdx.x;
    const int w   = t >> 6;
    const int l   = t & 63;
    const int q   = l >> 4;
    const int r16 = l & 15;
    const int wr  = w >> 1;
    const int wc  = w & 1;

    const int m0 = (int)(blockIdx.x >> 2) * MT2;   // 2 m-blocks
    const int n0 = (int)(blockIdx.x & 3) * NT2;    // 4 n-blocks

    const int srow = l >> 3;
    const int cg   = (l & 7) ^ srow;

    auto stage = [&](int kt, int bufi) {       // 8 glds/wave
        const int k0 = kt * BK;
        #pragma unroll
        for (int j = 0; j < 4; ++j) {
            const int rowb = w * 32 + j * 8;
            const unsigned short* g = wsW + (size_t)(n0 + rowb + srow) * KAUG
                                          + CNN_C + k0 + cg * 8;
            glds16(g, &Bb[bufi][rowb][0]);
        }
        #pragma unroll
        for (int j = 0; j < 4; ++j) {
            const int rowa = w * 32 + j * 8;
            const unsigned short* g = wsL + (size_t)(m0 + rowa + srow) * LSTMH + k0 + cg * 8;
            glds16(g, &Ab[bufi][rowa][0]);
        }
    };

    f32x4 acc[4][4];
    #pragma unroll
    for (int mt = 0; mt < 4; ++mt)
        #pragma unroll
        for (int nt = 0; nt < 4; ++nt)
            acc[mt][nt] = (f32x4){0.f, 0.f, 0.f, 0.f};

    stage(0, 0);
    stage(1, 1);

    for (int kt = 0; kt < KTH; ++kt) {
        const int cur = kt & 1;
        if (kt + 1 < KTH) { asm volatile("s_waitcnt vmcnt(8)" ::: "memory"); }
        else              { asm volatile("s_waitcnt vmcnt(0)" ::: "memory"); }
        __builtin_amdgcn_s_barrier();
        #pragma unroll
        for (int ks = 0; ks < 2; ++ks) {
            const int cp = ((ks * 4 + q) ^ (r16 & 7)) * 8;
            bf16x8 af[4], bfr[4];
            #pragma unroll
            for (int mt = 0; mt < 4; ++mt)
                af[mt] = *(const bf16x8*)&Ab[cur][wr * 64 + mt * 16 + r16][cp];
            #pragma unroll
            for (int nt = 0; nt < 4; ++nt)
                bfr[nt] = *(const bf16x8*)&Bb[cur][wc * 64 + nt * 16 + r16][cp];
            #pragma unroll
            for (int mt = 0; mt < 4; ++mt)
                #pragma unroll
                for (int nt = 0; nt < 4; ++nt)
                    acc[mt][nt] = __builtin_amdgcn_mfma_f32_16x16x32_bf16(
                        af[mt], bfr[nt], acc[mt][nt], 0, 0, 0);
        }
        __builtin_amdgcn_s_barrier();
        if (kt + 2 < KTH) stage(kt + 2, cur);
    }

    // store H (fp32): row = m0 + wr*64 + mt*16 + q*4 + rr, col = n0 + wc*64 + nt*16 + r16
    #pragma unroll
    for (int mt = 0; mt < 4; ++mt)
        #pragma unroll
        for (int nt = 0; nt < 4; ++nt)
            #pragma unroll
            for (int rr = 0; rr < 4; ++rr) {
                const int row = m0 + wr * 64 + mt * 16 + q * 4 + rr;
                const int col = n0 + wc * 64 + nt * 16 + r16;
                wsH[(size_t)row * PROJ + col] = acc[mt][nt][rr];
            }
}

// ==== fast-path GEMM: gemm8's counted-vmcnt 2-ahead pipeline, K = CNN_C only ====
// (round-8 verified schedule; ~40.5 us at K=2560, expect ~32 at K=2048.)
// Epilogue adds H[b][p] (staged 4x128 into LDS) before tanh.
__global__ __launch_bounds__(256, 2) void gemm11(
    const unsigned short* __restrict__ wsW, const unsigned short* __restrict__ wsA,
    const float* __restrict__ wsH,
    const float* __restrict__ bl, const float* __restrict__ bc,
    const float* __restrict__ wat, float* __restrict__ out)
{
    __shared__ unsigned short Ab[2][MT2][BK];   // 32 KB
    __shared__ unsigned short Bb[2][NT2][BK];   // 32 KB

    const int t   = threadIdx.x;
    const int w   = t >> 6;
    const int l   = t & 63;
    const int q   = l >> 4;
    const int r16 = l & 15;
    const int wr  = w >> 1;          // wave grid 2x2, wave owns 64x64
    const int wc  = w & 1;

    // XCD-bijective swizzle: 392 = 8*49; 4 n-blocks of one m-panel stay adjacent.
    const int bid = (int)blockIdx.x;
    const int swz = (bid & 7) * (NBLK2 / 8) + (bid >> 3);
    const int m0  = (swz >> 2) * MT2;
    const int n0  = (swz & 3) * NT2;

    const int srow = l >> 3;
    const int cg   = (l & 7) ^ srow;

    auto stage = [&](int kt, int bufi) {       // 8 glds/wave, uniform cnn path
        const int k0 = kt * BK;
        #pragma unroll
        for (int j = 0; j < 4; ++j) {
            const int rowb = w * 32 + j * 8;
            const unsigned short* g = wsW + (size_t)(n0 + rowb + srow) * KAUG + k0 + cg * 8;
            glds16(g, &Bb[bufi][rowb][0]);
        }
        #pragma unroll
        for (int j = 0; j < 4; ++j) {
            const int rowa = w * 32 + j * 8;
            const unsigned short* g = wsA + (size_t)(m0 + rowa + srow) * CNN_C + k0 + cg * 8;
            glds16(g, &Ab[bufi][rowa][0]);
        }
    };

    f32x4 acc[4][4];
    #pragma unroll
    for (int mt = 0; mt < 4; ++mt)
        #pragma unroll
        for (int nt = 0; nt < 4; ++nt)
            acc[mt][nt] = (f32x4){0.f, 0.f, 0.f, 0.f};

    stage(0, 0);
    stage(1, 1);

    for (int kt = 0; kt < KT11; ++kt) {
        const int cur = kt & 1;
        if (kt + 1 < KT11) { asm volatile("s_waitcnt vmcnt(8)" ::: "memory"); }
        else               { asm volatile("s_waitcnt vmcnt(0)" ::: "memory"); }
        __builtin_amdgcn_s_barrier();
        #pragma unroll
        for (int ks = 0; ks < 2; ++ks) {
            const int cp = ((ks * 4 + q) ^ (r16 & 7)) * 8;
            bf16x8 af[4], bfr[4];
            #pragma unroll
            for (int mt = 0; mt < 4; ++mt)
                af[mt] = *(const bf16x8*)&Ab[cur][wr * 64 + mt * 16 + r16][cp];
            #pragma unroll
            for (int nt = 0; nt < 4; ++nt)
                bfr[nt] = *(const bf16x8*)&Bb[cur][wc * 64 + nt * 16 + r16][cp];
            #pragma unroll
            for (int mt = 0; mt < 4; ++mt)
                #pragma unroll
                for (int nt = 0; nt < 4; ++nt)
                    acc[mt][nt] = __builtin_amdgcn_mfma_f32_16x16x32_bf16(
                        af[mt], bfr[nt], acc[mt][nt], 0, 0, 0);
        }
        __builtin_amdgcn_s_barrier();
        if (kt + 2 < KT11) stage(kt + 2, cur);
    }

    // ---- epilogue: stage H rows (<=4 distinct b) into LDS, then tanh+dot ----
    float* Hsf = (float*)&Bb[0][0][0];        // 4 x 128 floats = 2 KB (Bb dead)
    float* zpf = (float*)&Ab[0][0][0];        // reduce scratch (Ab dead)
    const int b0 = m0 / 49;
    if (t < 128) {
        #pragma unroll
        for (int j = 0; j < 4; ++j) {
            const int bsrc = (b0 + j < BSZ) ? (b0 + j) : (BSZ - 1);
            Hsf[j * 128 + t] = wsH[(size_t)bsrc * PROJ + n0 + t];
        }
    }
    __syncthreads();

    int bidx[4][4];
    #pragma unroll
    for (int mt = 0; mt < 4; ++mt)
        #pragma unroll
        for (int rr = 0; rr < 4; ++rr)
            bidx[mt][rr] = (m0 + wr * 64 + mt * 16 + q * 4 + rr) / 49 - b0;

    float part[4][4];
    #pragma unroll
    for (int mt = 0; mt < 4; ++mt)
        #pragma unroll
        for (int rr = 0; rr < 4; ++rr) part[mt][rr] = 0.f;
    #pragma unroll
    for (int nt = 0; nt < 4; ++nt) {
        const int colL = wc * 64 + nt * 16 + r16;
        const int p = n0 + colL;
        const float bb = bl[p] + bc[p];
        const float wa = wat[p];
        #pragma unroll
        for (int mt = 0; mt < 4; ++mt)
            #pragma unroll
            for (int rr = 0; rr < 4; ++rr)
                part[mt][rr] += tanh_fast(acc[mt][nt][rr] + bb
                                          + Hsf[bidx[mt][rr] * 128 + colL]) * wa;
    }
    #pragma unroll
    for (int mt = 0; mt < 4; ++mt)
        #pragma unroll
        for (int rr = 0; rr < 4; ++rr) {
            float v = part[mt][rr];
            v += __shfl_xor(v, 1);
            v += __shfl_xor(v, 2);
            v += __shfl_xor(v, 4);
            v += __shfl_xor(v, 8);            // sum over 16 cols (r16 group)
            if (r16 == 0) zpf[wc * MT2 + wr * 64 + mt * 16 + q * 4 + rr] = v;
        }
    __syncthreads();
    if (t < MT2) {
        const float v = zpf[t] + zpf[MT2 + t];
        const int row = m0 + t;
        const int b2  = row / 49;
        const int g2  = row - b2 * 49;
        atomicAdd(&out[g2 * BSZ + b2], v);    // scrambled position
    }
}

// ==== fallback (no workspace): verified convert-in-kernel GEMM ====
__global__ __launch_bounds__(256, 4) void gemm_k(
    const float* __restrict__ lstm, const float* __restrict__ cnn,
    const float* __restrict__ Wc,   const float* __restrict__ Wl,
    const float* __restrict__ bl,   const float* __restrict__ bc,
    const float* __restrict__ wat,  float* __restrict__ out)
{
    __shared__ unsigned short Ash[MT][BK];
    __shared__ unsigned short Bsh[NT][BK];
    __shared__ float zp[4][MT];

    const int t   = threadIdx.x;
    const int w   = t >> 6;
    const int l   = t & 63;
    const int q   = l >> 4;
    const int r16 = l & 15;

    const int bid = (int)blockIdx.x;
    const int swz = (bid & 7) * (NBLK / 8) + (bid >> 3);
    const int m0 = (swz >> 2) * MT;
    const int n0 = (swz & 3) * NT;

    const int ra  = t >> 2;
    const int ca0 = t & 3;
    const int sa  = ra & 7;
    const int grow = m0 + ra;
    const int ab   = grow / 49;
    const int ag   = grow - ab * 49;
    const float* cnnb  = cnn + ((size_t)ab * GRID_N + ag) * CNN_C;
    const float* lstmb = lstm + (size_t)ab * LSTMH;

    f32x4 acc[4][2];
    #pragma unroll
    for (int mt = 0; mt < 4; ++mt)
        #pragma unroll
        for (int nt = 0; nt < 2; ++nt)
            acc[mt][nt] = (f32x4){0.f, 0.f, 0.f, 0.f};

    float4 fa0, fa1, fa2, fa3;

    auto a_load = [&](int k0) {
        const float* s = (k0 < CNN_C) ? (cnnb + k0) : (lstmb + (k0 - CNN_C));
        const float4* p0 = (const float4*)(s + ca0 * 8);
        const float4* p1 = (const float4*)(s + (ca0 + 4) * 8);
        fa0 = p0[0]; fa1 = p0[1];
        fa2 = p1[0]; fa3 = p1[1];
    };
    auto a_write = [&]() {
        float f[8];
        *(float4*)&f[0] = fa0; *(float4*)&f[4] = fa1;
        *(uint4*)&Ash[ra][(ca0 ^ sa) * 8] = pack8f(f);
        *(float4*)&f[0] = fa2; *(float4*)&f[4] = fa3;
        *(uint4*)&Ash[ra][((ca0 + 4) ^ sa) * 8] = pack8f(f);
    };
    auto b_stage = [&](int k0) {
        const int rb = t >> 1;
        const int hb = t & 1;
        const float* s = (k0 < CNN_C) ? (Wc + (size_t)(n0 + rb) * CNN_C + k0)
                                      : (Wl + (size_t)(n0 + rb) * LSTMH + (k0 - CNN_C));
        const int sw = rb & 7;
        #pragma unroll
        for (int c = 0; c < 4; ++c) {
            const int cc = hb * 4 + c;
            float f[8];
            *(float4*)&f[0] = ((const float4*)(s + cc * 8))[0];
            *(float4*)&f[4] = ((const float4*)(s + cc * 8))[1];
            *(uint4*)&Bsh[rb][(cc ^ sw) * 8] = pack8f(f);
        }
    };

    a_load(0);
    a_write();
    b_stage(0);

    for (int kt = 0; kt < KTILES; ++kt) {
        __syncthreads();
        const bool more = (kt + 1 < KTILES);
        if (more) a_load((kt + 1) * BK);
        #pragma unroll
        for (int ks = 0; ks < 2; ++ks) {
            const int cp = ((ks * 4 + q) ^ (r16 & 7)) * 8;
            bf16x8 af[4], bfr[2];
            #pragma unroll
            for (int mt = 0; mt < 4; ++mt)
                af[mt] = *(const bf16x8*)&Ash[mt * 16 + r16][cp];
            #pragma unroll
            for (int nt = 0; nt < 2; ++nt)
                bfr[nt] = *(const bf16x8*)&Bsh[w * 32 + nt * 16 + r16][cp];
            #pragma unroll
            for (int mt = 0; mt < 4; ++mt)
                #pragma unroll
                for (int nt = 0; nt < 2; ++nt)
                    acc[mt][nt] = __builtin_amdgcn_mfma_f32_16x16x32_bf16(
                        af[mt], bfr[nt], acc[mt][nt], 0, 0, 0);
        }
        __syncthreads();
        if (more) { a_write(); b_stage((kt + 1) * BK); }
    }

    float part[4][4];
    #pragma unroll
    for (int mt = 0; mt < 4; ++mt)
        #pragma unroll
        for (int rr = 0; rr < 4; ++rr) part[mt][rr] = 0.f;
    #pragma unroll
    for (int nt = 0; nt < 2; ++nt) {
        const int p = n0 + w * 32 + nt * 16 + r16;
        const float bb = bl[p] + bc[p];
        const float wa = wat[p];
        #pragma unroll
        for (int mt = 0; mt < 4; ++mt)
            #pragma unroll
            for (int rr = 0; rr < 4; ++rr)
                part[mt][rr] += tanh_fast(acc[mt][nt][rr] + bb) * wa;
    }
    #pragma unroll
    for (int mt = 0; mt < 4; ++mt)
        #pragma unroll
        for (int rr = 0; rr < 4; ++rr) {
            float v = part[mt][rr];
            v += __shfl_xor(v, 1);
            v += __shfl_xor(v, 2);
            v += __shfl_xor(v, 4);
            v += __shfl_xor(v, 8);
            if (r16 == 0) zp[w][mt * 16 + q * 4 + rr] = v;
        }
    __syncthreads();
    if (t < MT) {
        const float v = zp[0][t] + zp[1][t] + zp[2][t] + zp[3][t];
        const int row = m0 + t;
        const int b2  = row / 49;
        const int g2  = row - b2 * 49;
        atomicAdd(&out[g2 * BSZ + b2], v);
    }
}

// Row softmax over 49 elements, in place. One wave per row.
__global__ __launch_bounds__(64) void softmax_rows(float* __restrict__ out)
{
    const int i = blockIdx.x;
    const int j = threadIdx.x;
    float x = (j < GRID_N) ? out[i * GRID_N + j] : -1e30f;
    float m = x;
    #pragma unroll
    for (int off = 32; off > 0; off >>= 1) m = fmaxf(m, __shfl_xor(m, off));
    float e = (j < GRID_N) ? __expf(x - m) : 0.f;
    float s = e;
    #pragma unroll
    for (int off = 32; off > 0; off >>= 1) s += __shfl_xor(s, off);
    if (j < GRID_N) out[i * GRID_N + j] = e / s;
}

extern "C" void kernel_launch(void* const* d_in, const int* in_sizes, int n_in,
                              void* d_out, int out_size, void* d_ws, size_t ws_size,
                              hipStream_t stream)
{
    const float* lstm = (const float*)d_in[0];
    const float* cnn  = (const float*)d_in[1];
    const float* Wl   = (const float*)d_in[2];
    const float* bl   = (const float*)d_in[3];
    const float* Wc   = (const float*)d_in[4];
    const float* bc   = (const float*)d_in[5];
    const float* wat  = (const float*)d_in[6];
    float* out = (float*)d_out;

    const size_t szW = (size_t)PROJ * KAUG * sizeof(unsigned short);    // 2.62 MB
    const size_t szA = (size_t)M_TOT * CNN_C * sizeof(unsigned short);  // 51.4 MB
    const size_t szL = (size_t)BSZ * LSTMH * sizeof(unsigned short);    // 0.26 MB
    const size_t szH = (size_t)BSZ * PROJ * sizeof(float);              // 0.52 MB

    if (ws_size >= szW + szA + szL + szH) {
        unsigned short* wsW = (unsigned short*)d_ws;
        unsigned short* wsA = wsW + (size_t)PROJ * KAUG;
        unsigned short* wsL = wsA + (size_t)M_TOT * CNN_C;
        float*          wsH = (float*)(wsL + (size_t)BSZ * LSTMH);
        prep_all<<<dim3(PBLK), dim3(256), 0, stream>>>(cnn, lstm, Wc, Wl, wsW, wsA, wsL, out);
        h_gemm<<<dim3(8), dim3(256), 0, stream>>>(wsL, wsW, wsH);
        gemm11<<<dim3(NBLK2), dim3(256), 0, stream>>>(wsW, wsA, wsH, bl, bc, wat, out);
    } else {
        hipMemsetAsync(out, 0, (size_t)out_size * sizeof(float), stream);
        gemm_k<<<dim3(NBLK), dim3(256), 0, stream>>>(lstm, cnn, Wc, Wl, bl, bc, wat, out);
    }
    softmax_rows<<<dim3(BSZ), dim3(64), 0, stream>>>(out);
}